// Round 4
// baseline (1466.401 us; speedup 1.0000x reference)
//
#include <hip/hip_runtime.h>

// ---------------------------------------------------------------------------
// GCN 2-layer forward on MI355X.
// R4: agg1/agg2 dim-sliced (16-dim slices, slice-major h layouts) with
// XCD-pinned blocks (blockIdx%8) + 2-phase soft ordering so each XCD's 4MB L2
// holds one 3.2MB slice -> gathers become L2 hits instead of 800MB L3 misses.
// csr_src streamed with nontemporal loads (read 16x) to avoid polluting L2.
// Pipeline: hist -> bscan -> scatter -> build -> packW -> GEMM1(MFMA,
// slice-major out) -> agg1(+relu, row-major out) -> GEMM2(slice-major out)
// -> agg2 -> d_out(fp32)
// ---------------------------------------------------------------------------

typedef short s16x8 __attribute__((ext_vector_type(8)));   // 8 bf16 = 4 VGPRs
typedef float f32x4 __attribute__((ext_vector_type(4)));

static constexpr int IN_DIM = 512;
static constexpr int HID = 256;
static constexpr int OUTD = 64;

static constexpr int BKT_SHIFT = 8;           // 256 nodes / bucket
static constexpr int MAX_NB = 400;            // >= ceil(100000/256)=391
static constexpr int CAP_BIN = 32;            // scatter LDS bin depth
static constexpr int EDGES_PER_BLOCK = 8192;  // scatter chunk

static __device__ __forceinline__ float bf2f(unsigned short u) {
  unsigned int x = ((unsigned int)u) << 16;
  float f;
  __builtin_memcpy(&f, &x, 4);
  return f;
}
static __device__ __forceinline__ unsigned short f2bf(float f) {
  unsigned int x;
  __builtin_memcpy(&x, &f, 4);
  unsigned int r = x + 0x7fffu + ((x >> 16) & 1u);  // RNE
  return (unsigned short)(r >> 16);
}

// ---------------- graph preprocessing (bucketed CSR build) ----------------

__global__ __launch_bounds__(256) void hist_kernel(
    const int* __restrict__ dst, int E, unsigned* __restrict__ bucket_count,
    int NB) {
  __shared__ unsigned cnt[512];
  for (int i = threadIdx.x; i < 512; i += 256) cnt[i] = 0;
  __syncthreads();
  for (int e = blockIdx.x * blockDim.x + threadIdx.x; e < E;
       e += gridDim.x * blockDim.x)
    atomicAdd(&cnt[dst[e] >> BKT_SHIFT], 1u);
  __syncthreads();
  for (int i = threadIdx.x; i < NB; i += 256)
    if (cnt[i]) atomicAdd(&bucket_count[i], cnt[i]);
}

__global__ __launch_bounds__(512) void bscan_kernel(
    const unsigned* __restrict__ bucket_count, int NB, int E, int Nn,
    unsigned* __restrict__ bucket_base, unsigned* __restrict__ bucket_cursor,
    unsigned* __restrict__ row_start) {
  __shared__ unsigned s[512];
  int tid = threadIdx.x;
  unsigned v = (tid < NB) ? bucket_count[tid] : 0u;
  s[tid] = v;
  __syncthreads();
  for (int off = 1; off < 512; off <<= 1) {
    unsigned t = (tid >= off) ? s[tid - off] : 0u;
    __syncthreads();
    s[tid] += t;
    __syncthreads();
  }
  unsigned excl = s[tid] - v;
  if (tid < NB) {
    bucket_base[tid] = excl;
    bucket_cursor[tid] = excl;
  }
  if (tid == 0) {
    bucket_base[NB] = (unsigned)E;
    row_start[Nn] = (unsigned)E;
  }
}

// bin edges by dst-bucket; entry = (src<<8)|(dst&255) (src<2^17 -> 25 bits)
__global__ __launch_bounds__(256) void scatter_kernel(
    const int* __restrict__ src, const int* __restrict__ dst, int E,
    unsigned* __restrict__ bucket_cursor, unsigned* __restrict__ entry_buf) {
  __shared__ unsigned cnt[MAX_NB];
  __shared__ unsigned poss[MAX_NB];
  __shared__ unsigned buf[MAX_NB * CAP_BIN];
  const int tid = threadIdx.x;
  const int e0 = blockIdx.x * EDGES_PER_BLOCK;
  const int e1 = min(E, e0 + EDGES_PER_BLOCK);
  for (int i = tid; i < MAX_NB; i += 256) cnt[i] = 0;
  __syncthreads();
  for (int e = e0 + tid; e < e1; e += 256) {
    int d = dst[e];
    unsigned entry = (((unsigned)src[e]) << 8) | ((unsigned)d & 255u);
    int bkt = d >> BKT_SHIFT;
    unsigned slot = atomicAdd(&cnt[bkt], 1u);
    if (slot < CAP_BIN) {
      buf[bkt * CAP_BIN + slot] = entry;
    } else {  // rare overflow: direct scattered write
      unsigned pos = atomicAdd(&bucket_cursor[bkt], 1u);
      entry_buf[pos] = entry;
    }
  }
  __syncthreads();
  for (int b = tid; b < MAX_NB; b += 256) {
    unsigned c = min(cnt[b], (unsigned)CAP_BIN);
    poss[b] = c ? atomicAdd(&bucket_cursor[b], c) : 0u;
  }
  __syncthreads();
  for (int b0 = 0; b0 < MAX_NB; b0 += 8) {
    int b = b0 + (tid >> 5);
    int i = tid & 31;
    unsigned c = min(cnt[b], (unsigned)CAP_BIN);
    if ((unsigned)i < c) entry_buf[poss[b] + i] = buf[b * CAP_BIN + i];
  }
}

// one block per bucket: LDS counting sort -> csr written into the bucket's
// 32KB window; emits dinv + row_start as byproducts.
__global__ __launch_bounds__(256) void build_kernel(
    const unsigned* __restrict__ entry_buf,
    const unsigned* __restrict__ bucket_base, int Nn,
    int* __restrict__ csr_src, unsigned* __restrict__ row_start,
    float* __restrict__ dinv) {
  __shared__ unsigned hist[256];
  __shared__ unsigned scn[256];
  const int tid = threadIdx.x;
  const int b = blockIdx.x;
  const unsigned nb0 = bucket_base[b];
  const int n_e = (int)(bucket_base[b + 1] - nb0);

  hist[tid] = 0;
  __syncthreads();
  for (int i = tid; i < n_e; i += 256)
    atomicAdd(&hist[entry_buf[nb0 + i] & 255u], 1u);
  __syncthreads();

  unsigned v = hist[tid];
  scn[tid] = v;
  __syncthreads();
  for (int off = 1; off < 256; off <<= 1) {
    unsigned t = (tid >= off) ? scn[tid - off] : 0u;
    __syncthreads();
    scn[tid] += t;
    __syncthreads();
  }
  unsigned excl = scn[tid] - v;
  __syncthreads();
  scn[tid] = excl;

  int node = (b << BKT_SHIFT) + tid;
  if (node < Nn) {
    dinv[node] = rsqrtf((float)v + 1.0f);  // +1 self loop
    row_start[node] = nb0 + excl;
  }
  hist[tid] = 0;  // reuse as per-node rank counters
  __syncthreads();

  for (int i = tid; i < n_e; i += 256) {
    unsigned en = entry_buf[nb0 + i];
    unsigned d = en & 255u;
    unsigned r = atomicAdd(&hist[d], 1u);
    csr_src[nb0 + scn[d] + r] = (int)(en >> 8);
  }
}

// W [K,N] fp32 -> Wt [N,K] bf16 (K contiguous: matches MFMA B-frag reads)
__global__ void pack_w_kernel(const float* __restrict__ W,
                              short* __restrict__ Wt, int K, int N) {
  int idx = blockIdx.x * blockDim.x + threadIdx.x;
  if (idx < K * N) {
    int n = idx / K, k = idx - n * K;
    Wt[idx] = (short)f2bf(W[(size_t)k * N + n]);
  }
}

// ---------------- GEMM: C[M,BN] = A[M,K] @ Wt^T, bf16 MFMA 16x16x32 ----------
// SLICE16: write C slice-major: C[(col/16)*M + row][16] (feeds sliced agg)
template <int BM, int BN, int WGM, int WGN, bool A_F32, bool SLICE16>
__launch_bounds__(256)
__global__ void gemm_kernel(const void* __restrict__ Av,
                            const short* __restrict__ Bt,
                            short* __restrict__ C, int M, int K) {
  constexpr int BK = 32;
  constexpr int N = BN;
  __shared__ short sA[BM * BK];
  __shared__ short sB[BN * BK];
  const int tid = threadIdx.x;
  const int wave = tid >> 6, lane = tid & 63;
  const int lm = lane & 15, lq = lane >> 4;
  const int row0 = blockIdx.x * BM;
  const int wm0 = (WGM > 1) ? wave * 64 : 0;
  const int wn0 = (WGN > 1) ? wave * 64 : 0;

  f32x4 acc[4][4];
#pragma unroll
  for (int i = 0; i < 4; i++)
#pragma unroll
    for (int j = 0; j < 4; j++) acc[i][j] = f32x4{0.f, 0.f, 0.f, 0.f};

  for (int k0 = 0; k0 < K; k0 += BK) {
    if constexpr (A_F32) {
      static_assert(BM == 64, "fp32 A staging assumes BM=64");
      const float* A = (const float*)Av;
      int m = tid >> 2, kc = tid & 3;
      int row = row0 + m;
      float4 f0 = make_float4(0, 0, 0, 0), f1 = f0;
      if (row < M) {
        const float4* pa = (const float4*)(A + (size_t)row * K + k0 + kc * 8);
        f0 = pa[0];
        f1 = pa[1];
      }
      s16x8 v;
      v[0] = (short)f2bf(f0.x); v[1] = (short)f2bf(f0.y);
      v[2] = (short)f2bf(f0.z); v[3] = (short)f2bf(f0.w);
      v[4] = (short)f2bf(f1.x); v[5] = (short)f2bf(f1.y);
      v[6] = (short)f2bf(f1.z); v[7] = (short)f2bf(f1.w);
      *(s16x8*)&sA[m * BK + kc * 8] = v;
    } else {
      const short* A = (const short*)Av;
#pragma unroll
      for (int i = 0; i < BM / 64; i++) {
        int idx = tid + i * 256;
        int m = idx >> 2, kc = idx & 3;
        int row = row0 + m;
        s16x8 v = {0, 0, 0, 0, 0, 0, 0, 0};
        if (row < M) v = *(const s16x8*)(A + (size_t)row * K + k0 + kc * 8);
        *(s16x8*)&sA[m * BK + kc * 8] = v;
      }
    }
#pragma unroll
    for (int i = 0; i < BN / 64; i++) {
      int idx = tid + i * 256;
      int n = idx >> 2, kc = idx & 3;
      *(s16x8*)&sB[n * BK + kc * 8] =
          *(const s16x8*)(Bt + (size_t)n * K + k0 + kc * 8);
    }
    __syncthreads();

    s16x8 af[4], bfr[4];
#pragma unroll
    for (int mi = 0; mi < 4; mi++)
      af[mi] = *(const s16x8*)&sA[(wm0 + mi * 16 + lm) * BK + lq * 8];
#pragma unroll
    for (int ni = 0; ni < 4; ni++)
      bfr[ni] = *(const s16x8*)&sB[(wn0 + ni * 16 + lm) * BK + lq * 8];
#pragma unroll
    for (int mi = 0; mi < 4; mi++)
#pragma unroll
      for (int ni = 0; ni < 4; ni++)
        acc[mi][ni] = __builtin_amdgcn_mfma_f32_16x16x32_bf16(
            af[mi], bfr[ni], acc[mi][ni], 0, 0, 0);
    __syncthreads();
  }

  // C/D layout (m89-verified): col = lane&15, row = (lane>>4)*4 + reg
#pragma unroll
  for (int mi = 0; mi < 4; mi++)
#pragma unroll
    for (int ni = 0; ni < 4; ni++) {
      const int col = wn0 + ni * 16 + lm;
      const size_t sbase = SLICE16 ? (size_t)(col >> 4) * M : 0;
#pragma unroll
      for (int r = 0; r < 4; r++) {
        int row = row0 + wm0 + mi * 16 + lq * 4 + r;
        if (row < M) {
          if constexpr (SLICE16)
            C[(sbase + row) * 16 + (col & 15)] = (short)f2bf(acc[mi][ni][r]);
          else
            C[(size_t)row * N + col] = (short)f2bf(acc[mi][ni][r]);
        }
      }
    }
}

// ---------------- aggregation (CSR, dim-sliced, XCD-pinned) ----------------
// Wave = 16 subgroups x 4 lanes; subgroup gathers one 32B row-slice per iter
// (16 rows in flight, 32 with unroll). Slice s lives on XCD s%8 (blockIdx%8);
// phase 0 = slices 0-7, phase 1 = slices 8-15 (soft ordering by blockIdx).
__global__ __launch_bounds__(256) void agg1_kernel(
    const short* __restrict__ h1s, const float* __restrict__ dinv,
    const unsigned* __restrict__ row_start, const int* __restrict__ csr_src,
    short* __restrict__ out, int n, int half_blocks) {
  int b = blockIdx.x;
  int slice, chunk;
  if (b < half_blocks) {
    slice = b & 7;
    chunk = b >> 3;
  } else {
    int b2 = b - half_blocks;
    slice = 8 + (b2 & 7);
    chunk = b2 >> 3;
  }
  const int lane = threadIdx.x & 63;
  const int wave = threadIdx.x >> 6;
  const int sub = lane >> 2;       // 16 subgroups / wave
  const int dl = (lane & 3) * 4;   // 4 dims / lane
  const short* hs = h1s + (size_t)slice * n * 16;
  const int base = chunk * 32 + wave * 8;
#pragma unroll 1
  for (int i = 0; i < 8; i++) {
    const int node = base + i;
    if (node >= n) break;  // wave-uniform
    const float di = dinv[node];
    float a0 = 0.f, a1 = 0.f, a2 = 0.f, a3 = 0.f;
    if (sub == 0) {  // self loop
      ushort4 v = *(const ushort4*)(hs + (size_t)node * 16 + dl);
      float ws = di * di;
      a0 = bf2f(v.x) * ws; a1 = bf2f(v.y) * ws;
      a2 = bf2f(v.z) * ws; a3 = bf2f(v.w) * ws;
    }
    const unsigned e1 = row_start[node + 1];
    unsigned e = row_start[node] + sub;
    for (; e + 16 < e1; e += 32) {
      int s0 = __builtin_nontemporal_load(csr_src + e);
      int s1 = __builtin_nontemporal_load(csr_src + e + 16);
      float w0 = dinv[s0] * di, w1 = dinv[s1] * di;
      ushort4 v0 = *(const ushort4*)(hs + (size_t)s0 * 16 + dl);
      ushort4 v1 = *(const ushort4*)(hs + (size_t)s1 * 16 + dl);
      a0 += bf2f(v0.x) * w0 + bf2f(v1.x) * w1;
      a1 += bf2f(v0.y) * w0 + bf2f(v1.y) * w1;
      a2 += bf2f(v0.z) * w0 + bf2f(v1.z) * w1;
      a3 += bf2f(v0.w) * w0 + bf2f(v1.w) * w1;
    }
    if (e < e1) {
      int s0 = __builtin_nontemporal_load(csr_src + e);
      float w0 = dinv[s0] * di;
      ushort4 v0 = *(const ushort4*)(hs + (size_t)s0 * 16 + dl);
      a0 += bf2f(v0.x) * w0; a1 += bf2f(v0.y) * w0;
      a2 += bf2f(v0.z) * w0; a3 += bf2f(v0.w) * w0;
    }
#pragma unroll
    for (int off = 4; off <= 32; off <<= 1) {
      a0 += __shfl_xor(a0, off);
      a1 += __shfl_xor(a1, off);
      a2 += __shfl_xor(a2, off);
      a3 += __shfl_xor(a3, off);
    }
    if (sub == 0) {  // relu + write row-major (gemm2 A-input)
      ushort4 o;
      o.x = f2bf(fmaxf(a0, 0.f)); o.y = f2bf(fmaxf(a1, 0.f));
      o.z = f2bf(fmaxf(a2, 0.f)); o.w = f2bf(fmaxf(a3, 0.f));
      *(ushort4*)(out + (size_t)node * HID + slice * 16 + dl) = o;
    }
  }
}

// layer 2: 4 slices x 16 dims; slice s on XCDs {2s,2s+1}. fp32 out.
__global__ __launch_bounds__(256) void agg2_kernel(
    const short* __restrict__ h2s, const float* __restrict__ dinv,
    const unsigned* __restrict__ row_start, const int* __restrict__ csr_src,
    float* __restrict__ out, int n) {
  const int b = blockIdx.x;
  const int slice = (b & 7) >> 1;
  const int chunk = (b >> 3) * 2 + (b & 1);
  const int lane = threadIdx.x & 63;
  const int wave = threadIdx.x >> 6;
  const int sub = lane >> 2;
  const int dl = (lane & 3) * 4;
  const short* hs = h2s + (size_t)slice * n * 16;
  const int base = chunk * 32 + wave * 8;
#pragma unroll 1
  for (int i = 0; i < 8; i++) {
    const int node = base + i;
    if (node >= n) break;
    const float di = dinv[node];
    float a0 = 0.f, a1 = 0.f, a2 = 0.f, a3 = 0.f;
    if (sub == 0) {
      ushort4 v = *(const ushort4*)(hs + (size_t)node * 16 + dl);
      float ws = di * di;
      a0 = bf2f(v.x) * ws; a1 = bf2f(v.y) * ws;
      a2 = bf2f(v.z) * ws; a3 = bf2f(v.w) * ws;
    }
    const unsigned e1 = row_start[node + 1];
    unsigned e = row_start[node] + sub;
    for (; e + 16 < e1; e += 32) {
      int s0 = __builtin_nontemporal_load(csr_src + e);
      int s1 = __builtin_nontemporal_load(csr_src + e + 16);
      float w0 = dinv[s0] * di, w1 = dinv[s1] * di;
      ushort4 v0 = *(const ushort4*)(hs + (size_t)s0 * 16 + dl);
      ushort4 v1 = *(const ushort4*)(hs + (size_t)s1 * 16 + dl);
      a0 += bf2f(v0.x) * w0 + bf2f(v1.x) * w1;
      a1 += bf2f(v0.y) * w0 + bf2f(v1.y) * w1;
      a2 += bf2f(v0.z) * w0 + bf2f(v1.z) * w1;
      a3 += bf2f(v0.w) * w0 + bf2f(v1.w) * w1;
    }
    if (e < e1) {
      int s0 = __builtin_nontemporal_load(csr_src + e);
      float w0 = dinv[s0] * di;
      ushort4 v0 = *(const ushort4*)(hs + (size_t)s0 * 16 + dl);
      a0 += bf2f(v0.x) * w0; a1 += bf2f(v0.y) * w0;
      a2 += bf2f(v0.z) * w0; a3 += bf2f(v0.w) * w0;
    }
#pragma unroll
    for (int off = 4; off <= 32; off <<= 1) {
      a0 += __shfl_xor(a0, off);
      a1 += __shfl_xor(a1, off);
      a2 += __shfl_xor(a2, off);
      a3 += __shfl_xor(a3, off);
    }
    if (sub == 0) {
      float4 o = make_float4(a0, a1, a2, a3);
      *(float4*)(out + (size_t)node * OUTD + slice * 16 + dl) = o;
    }
  }
}

// ---------------- launch ----------------

extern "C" void kernel_launch(void* const* d_in, const int* in_sizes, int n_in,
                              void* d_out, int out_size, void* d_ws,
                              size_t ws_size, hipStream_t stream) {
  const float* x = (const float*)d_in[0];
  const float* W1 = (const float*)d_in[1];
  const float* W2 = (const float*)d_in[2];
  const int* ei = (const int*)d_in[3];
  const int E = in_sizes[3] / 2;
  const int Nn = in_sizes[0] / IN_DIM;
  const int* src = ei;
  const int* dst = ei + E;
  const int NB = (Nn + 255) >> BKT_SHIFT;  // 391 (<= MAX_NB)

  char* p = (char*)d_ws;
  auto alloc = [&](size_t bytes) {
    char* r = p;
    p += (bytes + 255) & ~(size_t)255;
    return r;
  };
  unsigned* bucket_count = (unsigned*)alloc(512 * 4);
  unsigned* bucket_base = (unsigned*)alloc(512 * 4);
  unsigned* bucket_cursor = (unsigned*)alloc(512 * 4);
  unsigned* row_start = (unsigned*)alloc((size_t)(Nn + 1) * 4);
  float* dinv = (float*)alloc((size_t)Nn * 4);
  int* csr_src = (int*)alloc((size_t)E * 4);
  unsigned* entry_buf = (unsigned*)alloc((size_t)E * 4);
  short* Wt1 = (short*)alloc((size_t)IN_DIM * HID * 2);
  short* Wt2 = (short*)alloc((size_t)HID * OUTD * 2);
  short* h1s = (short*)alloc((size_t)Nn * HID * 2);   // slice-major [16][Nn][16]
  short* agg1 = (short*)alloc((size_t)Nn * HID * 2);  // row-major
  short* h2s = (short*)entry_buf;  // alias: dead after build (E*4 >= Nn*64*2)

  hipMemsetAsync(bucket_count, 0, 512 * 4, stream);
  hist_kernel<<<1024, 256, 0, stream>>>(dst, E, bucket_count, NB);
  bscan_kernel<<<1, 512, 0, stream>>>(bucket_count, NB, E, Nn, bucket_base,
                                      bucket_cursor, row_start);
  scatter_kernel<<<(E + EDGES_PER_BLOCK - 1) / EDGES_PER_BLOCK, 256, 0,
                   stream>>>(src, dst, E, bucket_cursor, entry_buf);
  build_kernel<<<NB, 256, 0, stream>>>(entry_buf, bucket_base, Nn, csr_src,
                                       row_start, dinv);
  pack_w_kernel<<<(IN_DIM * HID + 255) / 256, 256, 0, stream>>>(W1, Wt1,
                                                                IN_DIM, HID);
  pack_w_kernel<<<(HID * OUTD + 255) / 256, 256, 0, stream>>>(W2, Wt2, HID,
                                                              OUTD);
  gemm_kernel<64, 256, 1, 4, true, true>
      <<<(Nn + 63) / 64, 256, 0, stream>>>(x, Wt1, h1s, Nn, IN_DIM);
  {
    int chunks = (Nn + 31) / 32;   // 32 nodes / block
    int half = 8 * chunks;         // phase 0: slices 0-7
    agg1_kernel<<<2 * half, 256, 0, stream>>>(h1s, dinv, row_start, csr_src,
                                              agg1, Nn, half);
  }
  gemm_kernel<256, 64, 4, 1, false, true>
      <<<(Nn + 255) / 256, 256, 0, stream>>>(agg1, Wt2, h2s, Nn, HID);
  {
    int chunks = (Nn + 31) / 32;
    int pairs = (chunks + 1) / 2;
    agg2_kernel<<<8 * pairs, 256, 0, stream>>>(h2s, dinv, row_start, csr_src,
                                               (float*)d_out, Nn);
  }
}

// Round 5
// 707.674 us; speedup vs baseline: 2.0721x; 2.0721x over previous
//
#include <hip/hip_runtime.h>

// ---------------------------------------------------------------------------
// GCN 2-layer forward on MI355X.
// R5: revert agg1/agg2 to R3 forms (dim-slicing regressed 3.6x: per-edge
// overhead x16 outweighed the FETCH 800->326MB win). Prep slimmed: fixed
// 16384-entry bucket segments kill hist+bscan (cursor init fused into packW);
// build emits row_start + row_cnt (segments have gaps between buckets).
// Pipeline: packW+init -> scatter -> build -> GEMM1(MFMA) -> agg1(+relu) ->
//           GEMM2 -> agg2 -> d_out(fp32)
// ---------------------------------------------------------------------------

typedef short s16x8 __attribute__((ext_vector_type(8)));   // 8 bf16 = 4 VGPRs
typedef float f32x4 __attribute__((ext_vector_type(4)));

static constexpr int IN_DIM = 512;
static constexpr int HID = 256;
static constexpr int OUTD = 64;

static constexpr int BKT_SHIFT = 8;           // 256 nodes / bucket
static constexpr int MAX_NB = 400;            // >= ceil(100000/256)=391
static constexpr int CAP_BIN = 32;            // scatter LDS bin depth
static constexpr int EDGES_PER_BLOCK = 8192;  // scatter chunk
static constexpr int SEG_CAP = 16384;         // bucket segment (mean 8192 +90s)

static __device__ __forceinline__ float bf2f(unsigned short u) {
  unsigned int x = ((unsigned int)u) << 16;
  float f;
  __builtin_memcpy(&f, &x, 4);
  return f;
}
static __device__ __forceinline__ unsigned short f2bf(float f) {
  unsigned int x;
  __builtin_memcpy(&x, &f, 4);
  unsigned int r = x + 0x7fffu + ((x >> 16) & 1u);  // RNE
  return (unsigned short)(r >> 16);
}

// ---------------- fused: pack W1/W2 to bf16 [N,K] + init bucket cursors -----
__global__ __launch_bounds__(256) void pack_init_kernel(
    const float* __restrict__ W1, const float* __restrict__ W2,
    short* __restrict__ Wt1, short* __restrict__ Wt2,
    unsigned* __restrict__ bucket_cursor) {
  int idx = blockIdx.x * blockDim.x + threadIdx.x;
  if (idx < IN_DIM * HID) {  // Wt1[n*K+k] = W1[k*N+n]
    int n = idx / IN_DIM, k = idx - n * IN_DIM;
    Wt1[idx] = (short)f2bf(W1[(size_t)k * HID + n]);
  }
  if (idx < HID * OUTD) {
    int n = idx / HID, k = idx - n * HID;
    Wt2[idx] = (short)f2bf(W2[(size_t)k * OUTD + n]);
  }
  if (idx < 512) bucket_cursor[idx] = (unsigned)idx * SEG_CAP;
}

// bin edges by dst-bucket into fixed segments; entry = (src<<8)|(dst&255)
__global__ __launch_bounds__(256) void scatter_kernel(
    const int* __restrict__ src, const int* __restrict__ dst, int E,
    unsigned* __restrict__ bucket_cursor, unsigned* __restrict__ entry_buf) {
  __shared__ unsigned cnt[MAX_NB];
  __shared__ unsigned poss[MAX_NB];
  __shared__ unsigned buf[MAX_NB * CAP_BIN];
  const int tid = threadIdx.x;
  const int e0 = blockIdx.x * EDGES_PER_BLOCK;
  const int e1 = min(E, e0 + EDGES_PER_BLOCK);
  for (int i = tid; i < MAX_NB; i += 256) cnt[i] = 0;
  __syncthreads();
  for (int e = e0 + tid; e < e1; e += 256) {
    int d = dst[e];
    unsigned entry = (((unsigned)src[e]) << 8) | ((unsigned)d & 255u);
    int bkt = d >> BKT_SHIFT;
    unsigned slot = atomicAdd(&cnt[bkt], 1u);
    if (slot < CAP_BIN) {
      buf[bkt * CAP_BIN + slot] = entry;
    } else {  // rare overflow: direct scattered write
      unsigned pos = atomicAdd(&bucket_cursor[bkt], 1u);
      entry_buf[pos] = entry;
    }
  }
  __syncthreads();
  for (int b = tid; b < MAX_NB; b += 256) {
    unsigned c = min(cnt[b], (unsigned)CAP_BIN);
    poss[b] = c ? atomicAdd(&bucket_cursor[b], c) : 0u;
  }
  __syncthreads();
  for (int b0 = 0; b0 < MAX_NB; b0 += 8) {
    int b = b0 + (tid >> 5);
    int i = tid & 31;
    unsigned c = min(cnt[b], (unsigned)CAP_BIN);
    if ((unsigned)i < c) entry_buf[poss[b] + i] = buf[b * CAP_BIN + i];
  }
}

// one block per bucket: LDS counting sort -> csr in bucket segment; emits
// dinv, row_start, row_cnt.
__global__ __launch_bounds__(256) void build_kernel(
    const unsigned* __restrict__ entry_buf,
    const unsigned* __restrict__ bucket_cursor, int Nn,
    int* __restrict__ csr_src, unsigned* __restrict__ row_start,
    unsigned* __restrict__ row_cnt, float* __restrict__ dinv) {
  __shared__ unsigned hist[256];
  __shared__ unsigned scn[256];
  const int tid = threadIdx.x;
  const int b = blockIdx.x;
  const unsigned nb0 = (unsigned)b * SEG_CAP;
  const int n_e = (int)(bucket_cursor[b] - nb0);

  hist[tid] = 0;
  __syncthreads();
  for (int i = tid; i < n_e; i += 256)
    atomicAdd(&hist[entry_buf[nb0 + i] & 255u], 1u);
  __syncthreads();

  unsigned v = hist[tid];
  scn[tid] = v;
  __syncthreads();
  for (int off = 1; off < 256; off <<= 1) {
    unsigned t = (tid >= off) ? scn[tid - off] : 0u;
    __syncthreads();
    scn[tid] += t;
    __syncthreads();
  }
  unsigned excl = scn[tid] - v;
  __syncthreads();
  scn[tid] = excl;

  int node = (b << BKT_SHIFT) + tid;
  if (node < Nn) {
    dinv[node] = rsqrtf((float)v + 1.0f);  // +1 self loop
    row_start[node] = nb0 + excl;
    row_cnt[node] = v;
  }
  hist[tid] = 0;  // reuse as per-node rank counters
  __syncthreads();

  for (int i = tid; i < n_e; i += 256) {
    unsigned en = entry_buf[nb0 + i];
    unsigned d = en & 255u;
    unsigned r = atomicAdd(&hist[d], 1u);
    csr_src[nb0 + scn[d] + r] = (int)(en >> 8);
  }
}

// ---------------- GEMM: C[M,BN] = A[M,K] @ Wt^T, bf16 MFMA 16x16x32 ----------
template <int BM, int BN, int WGM, int WGN, bool A_F32>
__launch_bounds__(256)
__global__ void gemm_kernel(const void* __restrict__ Av,
                            const short* __restrict__ Bt,
                            short* __restrict__ C, int M, int K) {
  constexpr int BK = 32;
  constexpr int N = BN;
  __shared__ short sA[BM * BK];
  __shared__ short sB[BN * BK];
  const int tid = threadIdx.x;
  const int wave = tid >> 6, lane = tid & 63;
  const int lm = lane & 15, lq = lane >> 4;
  const int row0 = blockIdx.x * BM;
  const int wm0 = (WGM > 1) ? wave * 64 : 0;
  const int wn0 = (WGN > 1) ? wave * 64 : 0;

  f32x4 acc[4][4];
#pragma unroll
  for (int i = 0; i < 4; i++)
#pragma unroll
    for (int j = 0; j < 4; j++) acc[i][j] = f32x4{0.f, 0.f, 0.f, 0.f};

  for (int k0 = 0; k0 < K; k0 += BK) {
    if constexpr (A_F32) {
      static_assert(BM == 64, "fp32 A staging assumes BM=64");
      const float* A = (const float*)Av;
      int m = tid >> 2, kc = tid & 3;
      int row = row0 + m;
      float4 f0 = make_float4(0, 0, 0, 0), f1 = f0;
      if (row < M) {
        const float4* pa = (const float4*)(A + (size_t)row * K + k0 + kc * 8);
        f0 = pa[0];
        f1 = pa[1];
      }
      s16x8 v;
      v[0] = (short)f2bf(f0.x); v[1] = (short)f2bf(f0.y);
      v[2] = (short)f2bf(f0.z); v[3] = (short)f2bf(f0.w);
      v[4] = (short)f2bf(f1.x); v[5] = (short)f2bf(f1.y);
      v[6] = (short)f2bf(f1.z); v[7] = (short)f2bf(f1.w);
      *(s16x8*)&sA[m * BK + kc * 8] = v;
    } else {
      const short* A = (const short*)Av;
#pragma unroll
      for (int i = 0; i < BM / 64; i++) {
        int idx = tid + i * 256;
        int m = idx >> 2, kc = idx & 3;
        int row = row0 + m;
        s16x8 v = {0, 0, 0, 0, 0, 0, 0, 0};
        if (row < M) v = *(const s16x8*)(A + (size_t)row * K + k0 + kc * 8);
        *(s16x8*)&sA[m * BK + kc * 8] = v;
      }
    }
#pragma unroll
    for (int i = 0; i < BN / 64; i++) {
      int idx = tid + i * 256;
      int n = idx >> 2, kc = idx & 3;
      *(s16x8*)&sB[n * BK + kc * 8] =
          *(const s16x8*)(Bt + (size_t)n * K + k0 + kc * 8);
    }
    __syncthreads();

    s16x8 af[4], bfr[4];
#pragma unroll
    for (int mi = 0; mi < 4; mi++)
      af[mi] = *(const s16x8*)&sA[(wm0 + mi * 16 + lm) * BK + lq * 8];
#pragma unroll
    for (int ni = 0; ni < 4; ni++)
      bfr[ni] = *(const s16x8*)&sB[(wn0 + ni * 16 + lm) * BK + lq * 8];
#pragma unroll
    for (int mi = 0; mi < 4; mi++)
#pragma unroll
      for (int ni = 0; ni < 4; ni++)
        acc[mi][ni] = __builtin_amdgcn_mfma_f32_16x16x32_bf16(
            af[mi], bfr[ni], acc[mi][ni], 0, 0, 0);
    __syncthreads();
  }

  // C/D layout (m89-verified): col = lane&15, row = (lane>>4)*4 + reg
#pragma unroll
  for (int mi = 0; mi < 4; mi++)
#pragma unroll
    for (int ni = 0; ni < 4; ni++)
#pragma unroll
      for (int r = 0; r < 4; r++) {
        int row = row0 + wm0 + mi * 16 + lq * 4 + r;
        int col = wn0 + ni * 16 + lm;
        if (row < M) C[(size_t)row * N + col] = (short)f2bf(acc[mi][ni][r]);
      }
}

// ---------------- aggregation (CSR, no atomics) — R3-proven forms ----------
// layer 1: 256 dims. Half-wave = one 512B row (32 lanes x ushort8, 16B/lane);
// the two halves walk even/odd edges; 4-deep unroll -> 8 rows in flight.
__global__ __launch_bounds__(256) void agg1_kernel(
    const short* __restrict__ h1, const float* __restrict__ dinv,
    const unsigned* __restrict__ row_start, const unsigned* __restrict__ row_cnt,
    const int* __restrict__ csr_src, short* __restrict__ out, int n) {
  int node = blockIdx.x * 4 + (threadIdx.x >> 6);
  if (node >= n) return;
  const int lane = threadIdx.x & 63;
  const int half = lane >> 5;
  const int d0 = (lane & 31) * 8;  // 8 dims per lane
  const float di = dinv[node];
  float a[8];
#pragma unroll
  for (int j = 0; j < 8; j++) a[j] = 0.f;
  if (half == 0) {  // self loop
    s16x8 v = *(const s16x8*)(h1 + (size_t)node * HID + d0);
    float ws = di * di;
#pragma unroll
    for (int j = 0; j < 8; j++) a[j] += bf2f((unsigned short)v[j]) * ws;
  }
  unsigned e = row_start[node] + half;
  const unsigned e1 = row_start[node] + row_cnt[node];
  for (; e + 6 < e1; e += 8) {
    int s0 = csr_src[e], s1 = csr_src[e + 2];
    int s2 = csr_src[e + 4], s3 = csr_src[e + 6];
    float w0 = dinv[s0] * di, w1 = dinv[s1] * di;
    float w2 = dinv[s2] * di, w3 = dinv[s3] * di;
    s16x8 v0 = *(const s16x8*)(h1 + (size_t)s0 * HID + d0);
    s16x8 v1 = *(const s16x8*)(h1 + (size_t)s1 * HID + d0);
    s16x8 v2 = *(const s16x8*)(h1 + (size_t)s2 * HID + d0);
    s16x8 v3 = *(const s16x8*)(h1 + (size_t)s3 * HID + d0);
#pragma unroll
    for (int j = 0; j < 8; j++)
      a[j] += bf2f((unsigned short)v0[j]) * w0 + bf2f((unsigned short)v1[j]) * w1 +
              bf2f((unsigned short)v2[j]) * w2 + bf2f((unsigned short)v3[j]) * w3;
  }
  for (; e < e1; e += 2) {
    int s0 = csr_src[e];
    float w0 = dinv[s0] * di;
    s16x8 v0 = *(const s16x8*)(h1 + (size_t)s0 * HID + d0);
#pragma unroll
    for (int j = 0; j < 8; j++) a[j] += bf2f((unsigned short)v0[j]) * w0;
  }
#pragma unroll
  for (int j = 0; j < 8; j++) a[j] += __shfl_xor(a[j], 32);
  if (half == 0) {
    s16x8 o;
#pragma unroll
    for (int j = 0; j < 8; j++) o[j] = (short)f2bf(fmaxf(a[j], 0.f));
    *(s16x8*)(out + (size_t)node * HID + d0) = o;
  }
}

// layer 2: 64 dims. Quarter-wave = one 128B row (16 lanes x ushort4, 8B/lane);
// 4 quarters walk edge strides of 4; unroll 2 -> 8 rows in flight. fp32 out.
__global__ __launch_bounds__(256) void agg2_kernel(
    const short* __restrict__ h2, const float* __restrict__ dinv,
    const unsigned* __restrict__ row_start, const unsigned* __restrict__ row_cnt,
    const int* __restrict__ csr_src, float* __restrict__ out, int n) {
  int node = blockIdx.x * 4 + (threadIdx.x >> 6);
  if (node >= n) return;
  const int lane = threadIdx.x & 63;
  const int q = lane >> 4;
  const int d0 = (lane & 15) * 4;  // 4 dims per lane
  const float di = dinv[node];
  float a[4] = {0.f, 0.f, 0.f, 0.f};
  if (q == 0) {  // self loop
    ushort4 v = *(const ushort4*)(h2 + (size_t)node * OUTD + d0);
    float ws = di * di;
    a[0] = bf2f(v.x) * ws; a[1] = bf2f(v.y) * ws;
    a[2] = bf2f(v.z) * ws; a[3] = bf2f(v.w) * ws;
  }
  unsigned e = row_start[node] + q;
  const unsigned e1 = row_start[node] + row_cnt[node];
  for (; e + 4 < e1; e += 8) {
    int s0 = csr_src[e], s1 = csr_src[e + 4];
    float w0 = dinv[s0] * di, w1 = dinv[s1] * di;
    ushort4 v0 = *(const ushort4*)(h2 + (size_t)s0 * OUTD + d0);
    ushort4 v1 = *(const ushort4*)(h2 + (size_t)s1 * OUTD + d0);
    a[0] += bf2f(v0.x) * w0 + bf2f(v1.x) * w1;
    a[1] += bf2f(v0.y) * w0 + bf2f(v1.y) * w1;
    a[2] += bf2f(v0.z) * w0 + bf2f(v1.z) * w1;
    a[3] += bf2f(v0.w) * w0 + bf2f(v1.w) * w1;
  }
  for (; e < e1; e += 4) {
    int s0 = csr_src[e];
    float w0 = dinv[s0] * di;
    ushort4 v0 = *(const ushort4*)(h2 + (size_t)s0 * OUTD + d0);
    a[0] += bf2f(v0.x) * w0; a[1] += bf2f(v0.y) * w0;
    a[2] += bf2f(v0.z) * w0; a[3] += bf2f(v0.w) * w0;
  }
#pragma unroll
  for (int j = 0; j < 4; j++) {
    a[j] += __shfl_xor(a[j], 16);
    a[j] += __shfl_xor(a[j], 32);
  }
  if (q == 0) {
    float4 o = make_float4(a[0], a[1], a[2], a[3]);
    *(float4*)(out + (size_t)node * OUTD + d0) = o;
  }
}

// ---------------- launch ----------------

extern "C" void kernel_launch(void* const* d_in, const int* in_sizes, int n_in,
                              void* d_out, int out_size, void* d_ws,
                              size_t ws_size, hipStream_t stream) {
  const float* x = (const float*)d_in[0];
  const float* W1 = (const float*)d_in[1];
  const float* W2 = (const float*)d_in[2];
  const int* ei = (const int*)d_in[3];
  const int E = in_sizes[3] / 2;
  const int Nn = in_sizes[0] / IN_DIM;
  const int* src = ei;
  const int* dst = ei + E;
  const int NB = (Nn + 255) >> BKT_SHIFT;  // 391 (<= MAX_NB)

  char* p = (char*)d_ws;
  auto alloc = [&](size_t bytes) {
    char* r = p;
    p += (bytes + 255) & ~(size_t)255;
    return r;
  };
  unsigned* bucket_cursor = (unsigned*)alloc(512 * 4);
  unsigned* row_start = (unsigned*)alloc((size_t)Nn * 4);
  unsigned* row_cnt = (unsigned*)alloc((size_t)Nn * 4);
  float* dinv = (float*)alloc((size_t)Nn * 4);
  int* csr_src = (int*)alloc((size_t)MAX_NB * SEG_CAP * 4);     // 26.2MB
  unsigned* entry_buf = (unsigned*)alloc((size_t)MAX_NB * SEG_CAP * 4);
  short* Wt1 = (short*)alloc((size_t)IN_DIM * HID * 2);
  short* Wt2 = (short*)alloc((size_t)HID * OUTD * 2);
  short* h1 = (short*)alloc((size_t)Nn * HID * 2);
  short* agg1 = (short*)alloc((size_t)Nn * HID * 2);
  short* h2 = (short*)entry_buf;  // alias: entry_buf dead after build
                                  // (26.2MB >= Nn*OUTD*2 = 12.8MB)

  pack_init_kernel<<<(IN_DIM * HID + 255) / 256, 256, 0, stream>>>(
      W1, W2, Wt1, Wt2, bucket_cursor);
  scatter_kernel<<<(E + EDGES_PER_BLOCK - 1) / EDGES_PER_BLOCK, 256, 0,
                   stream>>>(src, dst, E, bucket_cursor, entry_buf);
  build_kernel<<<NB, 256, 0, stream>>>(entry_buf, bucket_cursor, Nn, csr_src,
                                       row_start, row_cnt, dinv);
  gemm_kernel<64, 256, 1, 4, true>
      <<<(Nn + 63) / 64, 256, 0, stream>>>(x, Wt1, h1, Nn, IN_DIM);
  agg1_kernel<<<(Nn + 3) / 4, 256, 0, stream>>>(h1, dinv, row_start, row_cnt,
                                                csr_src, agg1, Nn);
  gemm_kernel<256, 64, 4, 1, false>
      <<<(Nn + 255) / 256, 256, 0, stream>>>(agg1, Wt2, h2, Nn, HID);
  agg2_kernel<<<(Nn + 3) / 4, 256, 0, stream>>>(h2, dinv, row_start, row_cnt,
                                                csr_src, (float*)d_out, Nn);
}